// Round 7
// baseline (349.703 us; speedup 1.0000x reference)
//
#include <hip/hip_runtime.h>

#define TOTAL   160
#define NMAX    16
#define INDIM   1024
#define DIN     834
#define KPAD    864
#define GF      256
#define SS      1568
#define SPAD    1664   // 13 * 128

__constant__ int c_counts[16] = {6,14,10,8,16,12,9,11,7,13,10,10,8,12,6,8};
__constant__ int c_offs[16]   = {0,6,20,30,38,54,66,75,86,93,106,116,126,134,146,152};
__constant__ int c_t0[4] = {0, 12, 24, 36};   // s-tile ranges for upd (49 tiles of 32)
__constant__ int c_t1[4] = {12, 24, 36, 49};

using bf16x8 = __attribute__((ext_vector_type(8))) short;
using f32x4  = __attribute__((ext_vector_type(4))) float;
using us4    = __attribute__((ext_vector_type(4))) unsigned short;

__device__ inline unsigned short f2bf(float f) {
  union { float f; unsigned u; } v; v.f = f;
  const unsigned u = v.u;
  return (unsigned short)((u + 0x7FFFu + ((u >> 16) & 1u)) >> 16);
}
__device__ inline float bf2f(unsigned short h) {
  union { unsigned u; float f; } v; v.u = ((unsigned)h) << 16; return v.f;
}

// async 16B global -> LDS (wave-uniform LDS base + lane*16)
__device__ inline void gload_lds16(const void* g, void* l) {
  __builtin_amdgcn_global_load_lds(
      (const __attribute__((address_space(1))) unsigned*)g,
      (__attribute__((address_space(3))) unsigned*)l, 16, 0, 0);
}

// ---------------- conversion / utility kernels ----------------

__global__ __launch_bounds__(256) void wc_to_bf16(const float* __restrict__ Wc,
                                                  unsigned short* __restrict__ Ah) {
  const int idx = blockIdx.x * 256 + threadIdx.x;
  if (idx >= 4 * 256 * KPAD) return;
  const int k = idx % KPAD, gm = idx / KPAD;
  Ah[idx] = (k < DIN) ? f2bf(Wc[gm * DIN + k]) : (unsigned short)0;
}

// fm [16][834][1568] fp32 -> BhT [16][1568][864] bf16 (k-contiguous, zero-padded)
__global__ __launch_bounds__(256) void fm_to_bf16T(const float* __restrict__ fm,
                                                   unsigned short* __restrict__ BhT) {
  __shared__ float tile[32][33];
  const int b  = blockIdx.z;
  const int k0 = blockIdx.y * 32;
  const int s0 = blockIdx.x * 32;
  const int tx = threadIdx.x & 31, ty = threadIdx.x >> 5;
  const float* src = fm + (size_t)b * DIN * SS;
  #pragma unroll
  for (int r = 0; r < 4; ++r) {
    const int k = k0 + ty + r * 8;
    tile[ty + r * 8][tx] = (k < DIN) ? src[(size_t)k * SS + s0 + tx] : 0.f;
  }
  __syncthreads();
  unsigned short* dst = BhT + (size_t)b * SS * KPAD;
  #pragma unroll
  for (int r = 0; r < 4; ++r) {
    const int s = s0 + ty + r * 8;
    dst[(size_t)s * KPAD + k0 + tx] = f2bf(tile[tx][ty + r * 8]);
  }
}

__global__ __launch_bounds__(256) void pack_bf16(const float* __restrict__ src,
                                                 unsigned short* __restrict__ dst, int n4) {
  const int i = blockIdx.x * 256 + threadIdx.x;
  if (i >= n4) return;
  const float4 v = reinterpret_cast<const float4*>(src)[i];
  us4 o; o[0] = f2bf(v.x); o[1] = f2bf(v.y); o[2] = f2bf(v.z); o[3] = f2bf(v.w);
  reinterpret_cast<us4*>(dst)[i] = o;
}

__global__ __launch_bounds__(256) void zero_f32(float* __restrict__ p, int n) {
  const int i = blockIdx.x * 256 + threadIdx.x;
  if (i < n) p[i] = 0.f;
}

// flat_h = bf16(flatacc + emb)
__global__ __launch_bounds__(256) void pack_flat(const float* __restrict__ acc,
                                                 const float* __restrict__ emb,
                                                 unsigned short* __restrict__ flat_h) {
  const int i = blockIdx.x * 256 + threadIdx.x;
  if (i < TOTAL * INDIM) flat_h[i] = f2bf(acc[i] + emb[i]);
}

// ---------------- ctx GEMM, m97-style global_load_lds staging ----------------
// ctxT[z][s][f] = sum_k fmT[b][s][k] * Wc[g][f][k] + b_c[g][f]
// A rows = s (from BhT), B rows = f (from Ah). Unpadded LDS (32 shorts/row).
__global__ __launch_bounds__(256) void ctx_mfma(const unsigned short* __restrict__ Ah,
                                                const unsigned short* __restrict__ BhT,
                                                const float* __restrict__ b_c,
                                                unsigned short* __restrict__ ctxT) {
  __shared__ unsigned short As[128 * 32];   // s rows, k-contig
  __shared__ unsigned short Bs[128 * 32];   // f rows, k-contig
  const int z = blockIdx.z, g = z >> 4, b = z & 15;
  const int n0 = blockIdx.x * 128;          // f
  const int m0 = blockIdx.y * 128;          // s
  const int tid = threadIdx.x;
  const int wave = tid >> 6, lane = tid & 63;
  const int wm = (wave >> 1) * 64, wn = (wave & 1) * 64;
  const int quad = lane >> 4, lr = lane & 15;

  const unsigned short* Ag = BhT + (size_t)b * SS * KPAD;                     // rows s (junk past SS, in-ws)
  const unsigned short* Bg = Ah + (size_t)g * 256 * KPAD + (size_t)n0 * KPAD; // rows f (all valid)

  // two 16B chunks per thread per tile; LDS addr = base(wave,q) + lane*16
  const int c0 = wave * 128 + lane, c1 = c0 + 64;
  const int r0 = c0 >> 2, ko0 = (c0 & 3) * 8;
  const int r1 = c1 >> 2, ko1 = (c1 & 3) * 8;
  const size_t ga0 = (size_t)(m0 + r0) * KPAD + ko0;
  const size_t ga1 = (size_t)(m0 + r1) * KPAD + ko1;
  const size_t gb0 = (size_t)r0 * KPAD + ko0;
  const size_t gb1 = (size_t)r1 * KPAD + ko1;

  f32x4 acc[4][4];
  #pragma unroll
  for (int i = 0; i < 4; ++i)
    #pragma unroll
    for (int j = 0; j < 4; ++j) acc[i][j] = (f32x4){0.f, 0.f, 0.f, 0.f};

  for (int kt = 0; kt < 27; ++kt) {
    const int k0 = kt * 32;
    __syncthreads();
    gload_lds16(Ag + ga0 + k0, &As[c0 * 8]);
    gload_lds16(Ag + ga1 + k0, &As[c1 * 8]);
    gload_lds16(Bg + gb0 + k0, &Bs[c0 * 8]);
    gload_lds16(Bg + gb1 + k0, &Bs[c1 * 8]);
    __syncthreads();
    bf16x8 af[4], bfr[4];
    #pragma unroll
    for (int i = 0; i < 4; ++i)
      af[i] = *reinterpret_cast<const bf16x8*>(&As[(wm + i * 16 + lr) * 32 + quad * 8]);
    #pragma unroll
    for (int j = 0; j < 4; ++j)
      bfr[j] = *reinterpret_cast<const bf16x8*>(&Bs[(wn + j * 16 + lr) * 32 + quad * 8]);
    #pragma unroll
    for (int i = 0; i < 4; ++i)
      #pragma unroll
      for (int j = 0; j < 4; ++j)
        acc[i][j] = __builtin_amdgcn_mfma_f32_16x16x32_bf16(af[i], bfr[j], acc[i][j], 0, 0, 0);
  }

  unsigned short* Cz = ctxT + (size_t)z * SPAD * GF;
  const float* bias = b_c + g * GF;
  #pragma unroll
  for (int j = 0; j < 4; ++j) {
    const int n = n0 + wn + j * 16 + lr;
    const float bv = bias[n];
    #pragma unroll
    for (int i = 0; i < 4; ++i) {
      #pragma unroll
      for (int reg = 0; reg < 4; ++reg) {
        const int m = m0 + wm + i * 16 + quad * 4 + reg;   // < SPAD always
        Cz[(size_t)m * GF + n] = f2bf(acc[i][j][reg] + bv);
      }
    }
  }
}

// ---------------- emb: bf16 MFMA with in-staging fp32->bf16 ----------------
// emb[m][n] = sum_k actor[m][k] * W_a[n][k] + b_a[n]; writes emb fp32 + emb_h bf16.
// grid (16 n-tiles, 3 m-tiles), tile 64x64, K=1024.
__global__ __launch_bounds__(256) void emb_mfma(const float* __restrict__ actor,
                                                const float* __restrict__ Wa,
                                                const float* __restrict__ b_a,
                                                float* __restrict__ emb,
                                                unsigned short* __restrict__ emb_h) {
  __shared__ unsigned short As[64 * 40];
  __shared__ unsigned short Bs[64 * 40];
  const int n0 = blockIdx.x * 64, m0 = blockIdx.y * 64;
  const int tid = threadIdx.x;
  const int wave = tid >> 6, lane = tid & 63;
  const int wm = (wave >> 1) * 32, wn = (wave & 1) * 32;
  const int quad = lane >> 4, lr = lane & 15;
  const int r = tid >> 2, ko = (tid & 3) * 8;   // 8 fp32 elems per thread per operand
  const bool mval = (m0 + r < TOTAL);

  f32x4 acc[2][2];
  #pragma unroll
  for (int i = 0; i < 2; ++i)
    #pragma unroll
    for (int j = 0; j < 2; ++j) acc[i][j] = (f32x4){0.f, 0.f, 0.f, 0.f};

  const float4 zf4 = {0.f, 0.f, 0.f, 0.f};
  float4 ra0, ra1, rb0, rb1;
  ra0 = mval ? *reinterpret_cast<const float4*>(actor + (size_t)(m0 + r) * INDIM + ko) : zf4;
  ra1 = mval ? *reinterpret_cast<const float4*>(actor + (size_t)(m0 + r) * INDIM + ko + 4) : zf4;
  rb0 = *reinterpret_cast<const float4*>(Wa + (size_t)(n0 + r) * INDIM + ko);
  rb1 = *reinterpret_cast<const float4*>(Wa + (size_t)(n0 + r) * INDIM + ko + 4);

  for (int kt = 0; kt < 32; ++kt) {
    __syncthreads();
    {
      us4 a0, a1, b0, b1;
      a0[0]=f2bf(ra0.x); a0[1]=f2bf(ra0.y); a0[2]=f2bf(ra0.z); a0[3]=f2bf(ra0.w);
      a1[0]=f2bf(ra1.x); a1[1]=f2bf(ra1.y); a1[2]=f2bf(ra1.z); a1[3]=f2bf(ra1.w);
      b0[0]=f2bf(rb0.x); b0[1]=f2bf(rb0.y); b0[2]=f2bf(rb0.z); b0[3]=f2bf(rb0.w);
      b1[0]=f2bf(rb1.x); b1[1]=f2bf(rb1.y); b1[2]=f2bf(rb1.z); b1[3]=f2bf(rb1.w);
      *reinterpret_cast<us4*>(&As[r * 40 + ko])     = a0;
      *reinterpret_cast<us4*>(&As[r * 40 + ko + 4]) = a1;
      *reinterpret_cast<us4*>(&Bs[r * 40 + ko])     = b0;
      *reinterpret_cast<us4*>(&Bs[r * 40 + ko + 4]) = b1;
    }
    __syncthreads();
    if (kt < 31) {
      const int k0 = (kt + 1) * 32;
      ra0 = mval ? *reinterpret_cast<const float4*>(actor + (size_t)(m0 + r) * INDIM + k0 + ko) : zf4;
      ra1 = mval ? *reinterpret_cast<const float4*>(actor + (size_t)(m0 + r) * INDIM + k0 + ko + 4) : zf4;
      rb0 = *reinterpret_cast<const float4*>(Wa + (size_t)(n0 + r) * INDIM + k0 + ko);
      rb1 = *reinterpret_cast<const float4*>(Wa + (size_t)(n0 + r) * INDIM + k0 + ko + 4);
    }
    bf16x8 af[2], bfr[2];
    #pragma unroll
    for (int i = 0; i < 2; ++i)
      af[i] = *reinterpret_cast<const bf16x8*>(&As[(wm + i * 16 + lr) * 40 + quad * 8]);
    #pragma unroll
    for (int j = 0; j < 2; ++j)
      bfr[j] = *reinterpret_cast<const bf16x8*>(&Bs[(wn + j * 16 + lr) * 40 + quad * 8]);
    #pragma unroll
    for (int i = 0; i < 2; ++i)
      #pragma unroll
      for (int j = 0; j < 2; ++j)
        acc[i][j] = __builtin_amdgcn_mfma_f32_16x16x32_bf16(af[i], bfr[j], acc[i][j], 0, 0, 0);
  }

  #pragma unroll
  for (int i = 0; i < 2; ++i) {
    #pragma unroll
    for (int reg = 0; reg < 4; ++reg) {
      const int m = m0 + wm + i * 16 + quad * 4 + reg;
      if (m >= TOTAL) continue;
      #pragma unroll
      for (int j = 0; j < 2; ++j) {
        const int n = n0 + wn + j * 16 + lr;
        const float v = acc[i][j][reg] + b_a[n];
        emb[(size_t)m * INDIM + n] = v;
        emb_h[(size_t)m * INDIM + n] = f2bf(v);
      }
    }
  }
}

// ---------------- head: bf16 MFMA, out = relu(flat @ W_h^T) ----------------

__global__ __launch_bounds__(256) void head_mfma(const unsigned short* __restrict__ flat_h,
                                                 const unsigned short* __restrict__ Wh_h,
                                                 float* __restrict__ out) {
  __shared__ unsigned short As[64 * 40];
  __shared__ unsigned short Bs[64 * 40];
  const int g = blockIdx.z;
  const int n0 = blockIdx.x * 64, m0 = blockIdx.y * 64;
  const int tid = threadIdx.x;
  const int wave = tid >> 6, lane = tid & 63;
  const int wm = (wave >> 1) * 32, wn = (wave & 1) * 32;
  const int quad = lane >> 4, lr = lane & 15;
  const int r = tid >> 2, ko = (tid & 3) * 8;

  const unsigned short* Ag = flat_h + (size_t)m0 * INDIM + g * GF;
  const unsigned short* Bg = Wh_h + (size_t)g * GF * GF + (size_t)n0 * GF;

  f32x4 acc[2][2];
  #pragma unroll
  for (int i = 0; i < 2; ++i)
    #pragma unroll
    for (int j = 0; j < 2; ++j) acc[i][j] = (f32x4){0.f, 0.f, 0.f, 0.f};

  const uint4 zero4 = {0u, 0u, 0u, 0u};
  uint4 ra, rb;
  ra = (m0 + r < TOTAL) ? *reinterpret_cast<const uint4*>(Ag + (size_t)r * INDIM + ko) : zero4;
  rb = *reinterpret_cast<const uint4*>(Bg + (size_t)r * GF + ko);

  for (int kt = 0; kt < 8; ++kt) {
    __syncthreads();
    *reinterpret_cast<uint4*>(&As[r * 40 + ko]) = ra;
    *reinterpret_cast<uint4*>(&Bs[r * 40 + ko]) = rb;
    __syncthreads();
    if (kt < 7) {
      const int k0 = (kt + 1) * 32;
      ra = (m0 + r < TOTAL) ? *reinterpret_cast<const uint4*>(Ag + (size_t)r * INDIM + k0 + ko) : zero4;
      rb = *reinterpret_cast<const uint4*>(Bg + (size_t)r * GF + k0 + ko);
    }
    bf16x8 af[2], bfr[2];
    #pragma unroll
    for (int i = 0; i < 2; ++i)
      af[i] = *reinterpret_cast<const bf16x8*>(&As[(wm + i * 16 + lr) * 40 + quad * 8]);
    #pragma unroll
    for (int j = 0; j < 2; ++j)
      bfr[j] = *reinterpret_cast<const bf16x8*>(&Bs[(wn + j * 16 + lr) * 40 + quad * 8]);
    #pragma unroll
    for (int i = 0; i < 2; ++i)
      #pragma unroll
      for (int j = 0; j < 2; ++j)
        acc[i][j] = __builtin_amdgcn_mfma_f32_16x16x32_bf16(af[i], bfr[j], acc[i][j], 0, 0, 0);
  }

  #pragma unroll
  for (int i = 0; i < 2; ++i) {
    #pragma unroll
    for (int reg = 0; reg < 4; ++reg) {
      const int m = m0 + wm + i * 16 + quad * 4 + reg;
      if (m >= TOTAL) continue;
      #pragma unroll
      for (int j = 0; j < 2; ++j) {
        const int n = n0 + wn + j * 16 + lr;
        out[(size_t)m * INDIM + g * GF + n] = fmaxf(acc[i][j][reg], 0.f);
      }
    }
  }
}

// ---------------- adj via MFMA: PT[z][s][n] = logits^T, partial stats ----------------

__global__ __launch_bounds__(256) void adj_mfma(const unsigned short* __restrict__ ctxT,
                                                const unsigned short* __restrict__ emb_h,
                                                float* __restrict__ PT,
                                                float* __restrict__ pstat) {
  __shared__ float redm[4][16];
  __shared__ float redl[4][16];
  const int blk = blockIdx.x, z = blockIdx.y;
  const int g = z >> 4, b = z & 15;
  const int count = c_counts[b], off = c_offs[b];
  const int tid = threadIdx.x, wave = tid >> 6, lane = tid & 63;
  const int quad = lane >> 4, lr = lane & 15;
  const int sbase = blk * 128 + wave * 32;
  const unsigned short* Az = ctxT + (size_t)z * SPAD * GF;
  const bool bvalid = (lr < count);
  const unsigned short* Brow = emb_h + (size_t)(off + (bvalid ? lr : 0)) * INDIM + (g << 8);

  f32x4 acc[2] = {(f32x4){0.f, 0.f, 0.f, 0.f}, (f32x4){0.f, 0.f, 0.f, 0.f}};
  const bf16x8 zero8 = (bf16x8)(short)0;

  #pragma unroll
  for (int kk = 0; kk < 8; ++kk) {
    const int f = kk * 32 + quad * 8;
    bf16x8 bv8 = *reinterpret_cast<const bf16x8*>(Brow + f);
    if (!bvalid) bv8 = zero8;
    #pragma unroll
    for (int i = 0; i < 2; ++i) {
      const bf16x8 av8 = *reinterpret_cast<const bf16x8*>(
          Az + (size_t)(sbase + i * 16 + lr) * GF + f);
      acc[i] = __builtin_amdgcn_mfma_f32_16x16x32_bf16(av8, bv8, acc[i], 0, 0, 0);
    }
  }

  float* PTz = PT + (size_t)z * SS * 16;
  float mx = -3.0e38f;
  #pragma unroll
  for (int i = 0; i < 2; ++i)
    #pragma unroll
    for (int reg = 0; reg < 4; ++reg) {
      const int s = sbase + i * 16 + quad * 4 + reg;
      if (s < SS) {
        PTz[s * 16 + lr] = acc[i][reg];
        mx = fmaxf(mx, acc[i][reg]);
      }
    }
  float l = 0.f;
  #pragma unroll
  for (int i = 0; i < 2; ++i)
    #pragma unroll
    for (int reg = 0; reg < 4; ++reg) {
      const int s = sbase + i * 16 + quad * 4 + reg;
      if (s < SS) l += __expf(acc[i][reg] - mx);
    }
  #pragma unroll
  for (int d = 16; d < 64; d <<= 1) {
    const float om = __shfl_xor(mx, d, 64);
    const float ol = __shfl_xor(l, d, 64);
    const float M = fmaxf(mx, om);
    l = l * __expf(mx - M) + ol * __expf(om - M);
    mx = M;
  }
  if (lane < 16) { redm[wave][lr] = mx; redl[wave][lr] = l; }
  __syncthreads();
  if (tid < 16) {
    float M = -3.0e38f;
    #pragma unroll
    for (int w = 0; w < 4; ++w) M = fmaxf(M, redm[w][tid]);
    float L = 0.f;
    #pragma unroll
    for (int w = 0; w < 4; ++w) L += redl[w][tid] * __expf(redm[w][tid] - M);
    pstat[((size_t)z * 13 + blk) * 32 + tid]      = M;
    pstat[((size_t)z * 13 + blk) * 32 + 16 + tid] = L;
  }
}

__global__ __launch_bounds__(256) void stat_combine(const float* __restrict__ pstat,
                                                    float* __restrict__ mstat) {
  const int idx = blockIdx.x * 256 + threadIdx.x;
  if (idx >= 64 * 16) return;
  const int z = idx >> 4, n = idx & 15;
  float M = -3.0e38f;
  #pragma unroll
  for (int cc = 0; cc < 13; ++cc) M = fmaxf(M, pstat[((size_t)z * 13 + cc) * 32 + n]);
  float L = 0.f;
  #pragma unroll
  for (int cc = 0; cc < 13; ++cc)
    L += pstat[((size_t)z * 13 + cc) * 32 + 16 + n] *
         __expf(pstat[((size_t)z * 13 + cc) * 32 + n] - M);
  mstat[(z << 5) + n]      = M;
  mstat[(z << 5) + 16 + n] = 1.0f / L;
}

// ---------------- upd: O[n][f] += sum_s P[s][n] * ctxT[s][f] ----------------

__global__ __launch_bounds__(256) void upd_part(
    const unsigned short* __restrict__ ctxT, const float* __restrict__ PT,
    const float* __restrict__ mstat, float* __restrict__ flatacc)
{
  __shared__ float Bs[32][65];
  __shared__ float Ps[32][17];
  __shared__ float sm[16], sil[16];
  const int fc = blockIdx.x, sc = blockIdx.y, z = blockIdx.z;
  const int g = z >> 4, b = z & 15;
  const int count = c_counts[b], off = c_offs[b];
  const int f0 = fc << 6;
  const int t0 = c_t0[sc], t1 = c_t1[sc];
  const unsigned short* Az = ctxT + (size_t)z * SPAD * GF;
  const float* PTz = PT + (size_t)z * SS * 16;
  const int tid = threadIdx.x;
  if (tid < 16) sm[tid] = mstat[(z << 5) + tid];
  else if (tid < 32) sil[tid - 16] = mstat[(z << 5) + tid];
  __syncthreads();

  const int TX = tid & 63, TY = tid >> 6;
  float o[4] = {};
  for (int t = t0; t < t1; ++t) {
    const int s0 = t * 32;
    #pragma unroll
    for (int q = 0; q < 2; ++q) {
      const int idx = q * 256 + tid;
      const int nn = idx & 15, ss = idx >> 4;
      Ps[ss][nn] = __expf(PTz[(s0 + ss) * 16 + nn] - sm[nn]) * sil[nn];
    }
    #pragma unroll
    for (int q = 0; q < 4; ++q) {
      const int idx = q * 256 + tid;
      const int f2 = idx & 31, ss = idx >> 5;
      const unsigned pair = *reinterpret_cast<const unsigned*>(
          Az + (size_t)(s0 + ss) * GF + f0 + f2 * 2);
      Bs[ss][f2 * 2]     = bf2f((unsigned short)(pair & 0xFFFF));
      Bs[ss][f2 * 2 + 1] = bf2f((unsigned short)(pair >> 16));
    }
    __syncthreads();
    #pragma unroll
    for (int k = 0; k < 32; ++k) {
      const float bv = Bs[k][TX];
      #pragma unroll
      for (int i = 0; i < 4; ++i)
        o[i] = fmaf(Ps[k][(TY << 2) + i], bv, o[i]);
    }
    __syncthreads();
  }
  #pragma unroll
  for (int i = 0; i < 4; ++i) {
    const int n = (TY << 2) + i;
    if (n < count) {
      const int t = off + n;
      const int col = (g << 8) + f0 + TX;
      atomicAdd(&flatacc[t * INDIM + col], o[i]);
    }
  }
}

extern "C" void kernel_launch(void* const* d_in, const int* in_sizes, int n_in,
                              void* d_out, int out_size, void* d_ws, size_t ws_size,
                              hipStream_t stream) {
  (void)in_sizes; (void)n_in; (void)out_size; (void)ws_size;
  const float* actor = (const float*)d_in[0];
  const float* fmap  = (const float*)d_in[1];
  const float* W_a   = (const float*)d_in[2];
  const float* b_a   = (const float*)d_in[3];
  const float* W_c   = (const float*)d_in[4];
  const float* b_c   = (const float*)d_in[5];
  const float* W_h   = (const float*)d_in[6];
  float* out = (float*)d_out;
  char* ws = (char*)d_ws;

  float* emb             = (float*)(ws);                        // 655,360 B
  float* flatacc         = (float*)(ws + 655360);               // 655,360 B
  unsigned short* flat_h = (unsigned short*)(ws + 1310720);     // 327,680 B
  unsigned short* emb_h  = (unsigned short*)(ws + 1638400);     // 327,680 B
  float* mstat           = (float*)(ws + 1966080);              //   8,192 B
  float* PT              = (float*)(ws + 1974272);              // 6,422,528 B
  unsigned short* ctxT   = (unsigned short*)(ws + 8396800);     // 54,525,952 B
  unsigned short* Ah     = (unsigned short*)(ws + 62922752);    // 1,769,472 B
  float* pstat           = (float*)(ws + 62922752);             // aliases Ah (time-disjoint)
  unsigned short* BhT    = (unsigned short*)(ws + 64692224);    // 43,352,064 B
  unsigned short* Wh_h   = (unsigned short*)(ws + 108044288);   // 524,288 B (end 108,568,576)

  // 0) conversions + zeroing
  hipLaunchKernelGGL(wc_to_bf16, dim3((4 * 256 * KPAD + 255) / 256), dim3(256), 0, stream,
                     W_c, Ah);
  hipLaunchKernelGGL(fm_to_bf16T, dim3(49, 27, 16), dim3(256), 0, stream, fmap, BhT);
  hipLaunchKernelGGL(pack_bf16, dim3(256), dim3(256), 0, stream, W_h, Wh_h, 65536);
  hipLaunchKernelGGL(zero_f32, dim3(640), dim3(256), 0, stream, flatacc, TOTAL * INDIM);

  // 1) emb via bf16 MFMA (writes emb fp32 + emb_h bf16)
  hipLaunchKernelGGL(emb_mfma, dim3(16, 3), dim3(256), 0, stream,
                     actor, W_a, b_a, emb, emb_h);

  // 2) ctxT via bf16 MFMA with global_load_lds staging
  hipLaunchKernelGGL(ctx_mfma, dim3(2, 13, 64), dim3(256), 0, stream, Ah, BhT, b_c, ctxT);

  // 3) adj logits via MFMA -> PT + partial stats; combine
  hipLaunchKernelGGL(adj_mfma, dim3(13, 64), dim3(256), 0, stream, ctxT, emb_h, PT, pstat);
  hipLaunchKernelGGL(stat_combine, dim3(4), dim3(256), 0, stream, pstat, mstat);

  // 4) upd (f-split 4 x s-split 4) -> atomic partial O in flatacc
  hipLaunchKernelGGL(upd_part, dim3(4, 4, 64), dim3(256), 0, stream,
                     ctxT, PT, mstat, flatacc);

  // 4b) flat_h = bf16(flatacc + emb)
  hipLaunchKernelGGL(pack_flat, dim3(640), dim3(256), 0, stream, flatacc, emb, flat_h);

  // 5) out = relu(flat @ W_h^T) via bf16 MFMA
  hipLaunchKernelGGL(head_mfma, dim3(4, 3, 4), dim3(256), 0, stream, flat_h, Wh_h, out);
}